// Round 1
// baseline (1255.268 us; speedup 1.0000x reference)
//
#include <hip/hip_runtime.h>

// -------------------- degree --------------------
__global__ void count_deg(const int* __restrict__ dst, int* __restrict__ cnt, int E) {
    int e = blockIdx.x * blockDim.x + threadIdx.x;
    if (e < E) atomicAdd(&cnt[dst[e]], 1);
}

__global__ void deg_to_dis(const int* __restrict__ cnt, float* __restrict__ dis, int n) {
    int i = blockIdx.x * blockDim.x + threadIdx.x;
    if (i < n) dis[i] = rsqrtf((float)cnt[i] + 1.0f);
}

// -------------------- GEMM 512 -> 32 --------------------
// 256 threads = 8 rows x 32 cols; W1 (512x32 = 64KB) staged in LDS.
__global__ __launch_bounds__(256) void gemm512_32(const float* __restrict__ x,
        const float* __restrict__ W, float* __restrict__ h, int n) {
    __shared__ float w[512 * 32];
    for (int i = threadIdx.x; i < 512 * 32; i += 256) w[i] = W[i];
    __syncthreads();
    int r = threadIdx.x >> 5;
    int c = threadIdx.x & 31;
    int node = blockIdx.x * 8 + r;
    if (node >= n) return;
    const float4* x4 = (const float4*)(x + (size_t)node * 512);
    float acc = 0.f;
    #pragma unroll 4
    for (int k4 = 0; k4 < 128; ++k4) {
        float4 xv = x4[k4];
        int k = k4 * 4;
        acc += xv.x * w[(k + 0) * 32 + c];
        acc += xv.y * w[(k + 1) * 32 + c];
        acc += xv.z * w[(k + 2) * 32 + c];
        acc += xv.w * w[(k + 3) * 32 + c];
    }
    h[(size_t)node * 32 + c] = acc;
}

// -------------------- GEMM 32 -> 16 --------------------
__global__ __launch_bounds__(256) void gemm32_16(const float* __restrict__ xin,
        const float* __restrict__ W, float* __restrict__ h, int n) {
    __shared__ float w[32 * 16];
    if (threadIdx.x < 256) { w[threadIdx.x] = W[threadIdx.x]; w[threadIdx.x + 256] = W[threadIdx.x + 256]; }
    __syncthreads();
    int r = threadIdx.x >> 4;   // 0..15
    int c = threadIdx.x & 15;
    int node = blockIdx.x * 16 + r;
    if (node >= n) return;
    const float4* x4 = (const float4*)(xin + (size_t)node * 32);
    float acc = 0.f;
    #pragma unroll
    for (int k4 = 0; k4 < 8; ++k4) {
        float4 xv = x4[k4];
        int k = k4 * 4;
        acc += xv.x * w[(k + 0) * 16 + c];
        acc += xv.y * w[(k + 1) * 16 + c];
        acc += xv.z * w[(k + 2) * 16 + c];
        acc += xv.w * w[(k + 3) * 16 + c];
    }
    h[(size_t)node * 16 + c] = acc;
}

// -------------------- GEMM 16 -> 11 --------------------
__global__ __launch_bounds__(256) void gemm16_11(const float* __restrict__ xin,
        const float* __restrict__ W, float* __restrict__ h, int n) {
    __shared__ float w[16 * 11];
    if (threadIdx.x < 176) w[threadIdx.x] = W[threadIdx.x];
    __syncthreads();
    int r = threadIdx.x >> 4;
    int c = threadIdx.x & 15;
    int node = blockIdx.x * 16 + r;
    if (node >= n || c >= 11) return;
    const float4* x4 = (const float4*)(xin + (size_t)node * 16);
    float acc = 0.f;
    #pragma unroll
    for (int k4 = 0; k4 < 4; ++k4) {
        float4 xv = x4[k4];
        int k = k4 * 4;
        acc += xv.x * w[(k + 0) * 11 + c];
        acc += xv.y * w[(k + 1) * 11 + c];
        acc += xv.z * w[(k + 2) * 11 + c];
        acc += xv.w * w[(k + 3) * 11 + c];
    }
    h[(size_t)node * 11 + c] = acc;
}

// -------------------- edge message passing (atomic scatter) --------------------
template<int F>
__global__ void msg_pass(const int* __restrict__ src, const int* __restrict__ dst,
                         const float* __restrict__ dis, const float* __restrict__ h,
                         float* __restrict__ agg, int E) {
    unsigned gid = blockIdx.x * blockDim.x + threadIdx.x;
    int e = (int)(gid / F);
    int f = (int)(gid % F);
    if (e >= E) return;
    int s = src[e], d = dst[e];
    float norm = dis[s] * dis[d];
    atomicAdd(&agg[(size_t)d * F + f], h[(size_t)s * F + f] * norm);
}

// 16 lanes per edge, 11 active (layer 3)
__global__ void msg_pass11(const int* __restrict__ src, const int* __restrict__ dst,
                           const float* __restrict__ dis, const float* __restrict__ h,
                           float* __restrict__ agg, int E) {
    unsigned gid = blockIdx.x * blockDim.x + threadIdx.x;
    int e = (int)(gid >> 4);
    int f = (int)(gid & 15);
    if (e >= E || f >= 11) return;
    int s = src[e], d = dst[e];
    float norm = dis[s] * dis[d];
    atomicAdd(&agg[(size_t)d * 11 + f], h[(size_t)s * 11 + f] * norm);
}

// -------------------- self-loop + bias (+ ReLU), in place on agg --------------------
template<int F, bool RELU>
__global__ void self_bias(const float* __restrict__ h, const float* __restrict__ dis,
                          const float* __restrict__ b, float* __restrict__ agg, int n) {
    unsigned gid = blockIdx.x * blockDim.x + threadIdx.x;
    unsigned node = gid / F, f = gid % F;
    if (node >= (unsigned)n) return;
    float d2 = dis[node]; d2 *= d2;
    float v = agg[gid] + h[gid] * d2 + b[f];
    if (RELU) v = fmaxf(v, 0.f);
    agg[gid] = v;
}

// -------------------- final: self-loop + bias + log_softmax, in place on out --------------------
__global__ void finalize(const float* __restrict__ h3, const float* __restrict__ dis,
                         const float* __restrict__ b, float* __restrict__ out, int n) {
    int node = blockIdx.x * blockDim.x + threadIdx.x;
    if (node >= n) return;
    float d2 = dis[node]; d2 *= d2;
    float v[11];
    float m = -1e30f;
    #pragma unroll
    for (int c = 0; c < 11; ++c) {
        v[c] = out[(size_t)node * 11 + c] + h3[(size_t)node * 11 + c] * d2 + b[c];
        m = fmaxf(m, v[c]);
    }
    float s = 0.f;
    #pragma unroll
    for (int c = 0; c < 11; ++c) s += __expf(v[c] - m);
    float ls = __logf(s) + m;
    #pragma unroll
    for (int c = 0; c < 11; ++c) out[(size_t)node * 11 + c] = v[c] - ls;
}

extern "C" void kernel_launch(void* const* d_in, const int* in_sizes, int n_in,
                              void* d_out, int out_size, void* d_ws, size_t ws_size,
                              hipStream_t stream) {
    const float* x  = (const float*)d_in[0];
    const int*   ei = (const int*)d_in[1];
    const float* W1 = (const float*)d_in[2];
    const float* b1 = (const float*)d_in[3];
    const float* W2 = (const float*)d_in[4];
    const float* b2 = (const float*)d_in[5];
    const float* W3 = (const float*)d_in[6];
    const float* b3 = (const float*)d_in[7];
    float* out = (float*)d_out;

    const int n = in_sizes[0] / 512;
    const int E = in_sizes[1] / 2;
    const int* src = ei;
    const int* dst = ei + E;

    // workspace layout
    char* ws = (char*)d_ws;
    int*   cnt  = (int*)ws;                          // N ints
    float* dis  = (float*)(ws + (size_t)n * 4);      // N floats
    float* h1   = dis + n;                           // N*32 floats
    float* agg1 = h1 + (size_t)n * 32;               // N*32 floats (becomes out1, then h3)
    float* h2   = h1;                                // N*16 (reuses h1 low half)
    float* agg2 = h1 + (size_t)n * 16;               // N*16 (reuses h1 high half)
    float* h3   = agg1;                              // N*11 (reuses agg1)

    // ---- degrees ----
    hipMemsetAsync(cnt, 0, (size_t)n * 4, stream);
    count_deg<<<(E + 255) / 256, 256, 0, stream>>>(dst, cnt, E);
    deg_to_dis<<<(n + 255) / 256, 256, 0, stream>>>(cnt, dis, n);

    // ---- layer 1 ----
    gemm512_32<<<(n + 7) / 8, 256, 0, stream>>>(x, W1, h1, n);
    hipMemsetAsync(agg1, 0, (size_t)n * 32 * 4, stream);
    {
        unsigned long long tot = (unsigned long long)E * 32ull;
        msg_pass<32><<<(unsigned)((tot + 255) / 256), 256, 0, stream>>>(src, dst, dis, h1, agg1, E);
    }
    self_bias<32, true><<<(unsigned)(((size_t)n * 32 + 255) / 256), 256, 0, stream>>>(h1, dis, b1, agg1, n);

    // ---- layer 2 ----  (out1 lives in agg1)
    gemm32_16<<<(n + 15) / 16, 256, 0, stream>>>(agg1, W2, h2, n);
    hipMemsetAsync(agg2, 0, (size_t)n * 16 * 4, stream);
    {
        unsigned long long tot = (unsigned long long)E * 16ull;
        msg_pass<16><<<(unsigned)((tot + 255) / 256), 256, 0, stream>>>(src, dst, dis, h2, agg2, E);
    }
    self_bias<16, true><<<(unsigned)(((size_t)n * 16 + 255) / 256), 256, 0, stream>>>(h2, dis, b2, agg2, n);

    // ---- layer 3 ----  (out2 lives in agg2; h3 overwrites agg1)
    gemm16_11<<<(n + 15) / 16, 256, 0, stream>>>(agg2, W3, h3, n);
    hipMemsetAsync(out, 0, (size_t)n * 11 * 4, stream);
    {
        unsigned long long tot = (unsigned long long)E * 16ull;
        msg_pass11<<<(unsigned)((tot + 255) / 256), 256, 0, stream>>>(src, dst, dis, h3, out, E);
    }
    finalize<<<(n + 255) / 256, 256, 0, stream>>>(h3, dis, b3, out, n);
}

// Round 3
// 776.477 us; speedup vs baseline: 1.6166x; 1.6166x over previous
//
#include <hip/hip_runtime.h>

// ==================== degree / CSR build ====================

__global__ void count_deg(const int* __restrict__ dst, int* __restrict__ cnt, int E) {
    int e = blockIdx.x * blockDim.x + threadIdx.x;
    if (e < E) atomicAdd(&cnt[dst[e]], 1);
}

__global__ void deg_to_dis(const int* __restrict__ cnt, float* __restrict__ dis, int n) {
    int i = blockIdx.x * blockDim.x + threadIdx.x;
    if (i < n) dis[i] = rsqrtf((float)cnt[i] + 1.0f);
}

#define SCAN_ELEMS 1024  // 256 threads x 4

__global__ __launch_bounds__(256) void scan1(const int* __restrict__ cnt, int* __restrict__ start,
                                             int* __restrict__ blksum, int n) {
    __shared__ int sh[256];
    int base = blockIdx.x * SCAN_ELEMS;
    int idx = base + threadIdx.x * 4;
    int v0 = 0, v1 = 0, v2 = 0, v3 = 0;
    if (idx + 0 < n) v0 = cnt[idx + 0];
    if (idx + 1 < n) v1 = cnt[idx + 1];
    if (idx + 2 < n) v2 = cnt[idx + 2];
    if (idx + 3 < n) v3 = cnt[idx + 3];
    int sum = v0 + v1 + v2 + v3;
    sh[threadIdx.x] = sum;
    __syncthreads();
    for (int off = 1; off < 256; off <<= 1) {
        int t = (threadIdx.x >= off) ? sh[threadIdx.x - off] : 0;
        __syncthreads();
        sh[threadIdx.x] += t;
        __syncthreads();
    }
    if (threadIdx.x == 255) blksum[blockIdx.x] = sh[255];
    int run = sh[threadIdx.x] - sum;  // exclusive within block
    if (idx + 0 < n) start[idx + 0] = run;
    run += v0;
    if (idx + 1 < n) start[idx + 1] = run;
    run += v1;
    if (idx + 2 < n) start[idx + 2] = run;
    run += v2;
    if (idx + 3 < n) start[idx + 3] = run;
}

__global__ __launch_bounds__(256) void scan2(int* __restrict__ blksum, int nb) {
    __shared__ int sh[256];
    int t = threadIdx.x;
    int v = (t < nb) ? blksum[t] : 0;
    sh[t] = v;
    __syncthreads();
    for (int off = 1; off < 256; off <<= 1) {
        int u = (t >= off) ? sh[t - off] : 0;
        __syncthreads();
        sh[t] += u;
        __syncthreads();
    }
    if (t < nb) blksum[t] = sh[t] - v;  // exclusive
}

__global__ void scan3(int* __restrict__ start, const int* __restrict__ blksum, int n) {
    int i = blockIdx.x * blockDim.x + threadIdx.x;
    if (i < n) start[i] += blksum[i >> 10];  // i / SCAN_ELEMS
}

__global__ void fill_csr(const int* __restrict__ src, const int* __restrict__ dst,
                         const int* __restrict__ start, int* __restrict__ fill,
                         int* __restrict__ csr_src, int E) {
    int e = blockIdx.x * blockDim.x + threadIdx.x;
    if (e >= E) return;
    int d = dst[e];
    int pos = start[d] + atomicAdd(&fill[d], 1);
    csr_src[pos] = src[e];
}

// ==================== GEMMs (epilogue scales row by dis[node] -> g) ====================

// 512 -> 32. One node per thread, K chunked by 32, x staged in padded LDS.
__global__ __launch_bounds__(128) void gemm1(const float* __restrict__ x, const float* __restrict__ W,
                                             const float* __restrict__ dis, float* __restrict__ g, int n) {
    __shared__ float ws[32 * 32];
    __shared__ float xs[128][33];
    int tid = threadIdx.x;
    int node0 = blockIdx.x * 128;
    int node = node0 + tid;
    float acc[32];
    #pragma unroll
    for (int c = 0; c < 32; ++c) acc[c] = 0.f;

    for (int k0 = 0; k0 < 512; k0 += 32) {
        __syncthreads();
        // W chunk: 32x32 = 256 float4, 2 per thread
        #pragma unroll
        for (int r = 0; r < 2; ++r) {
            int fi = tid + r * 128;
            int k = fi >> 3, c4 = fi & 7;
            float4 wv = *(const float4*)(W + (size_t)(k0 + k) * 32 + c4 * 4);
            *((float4*)(ws + k * 32 + c4 * 4)) = wv;
        }
        // x chunk: 128 nodes x 32 = 1024 float4, 8 per thread (coalesced)
        #pragma unroll
        for (int r = 0; r < 8; ++r) {
            int fi = tid + r * 128;
            int nd = fi >> 3, k4 = fi & 7;
            int gn = min(node0 + nd, n - 1);
            float4 xv = *(const float4*)(x + (size_t)gn * 512 + k0 + k4 * 4);
            xs[nd][k4 * 4 + 0] = xv.x;
            xs[nd][k4 * 4 + 1] = xv.y;
            xs[nd][k4 * 4 + 2] = xv.z;
            xs[nd][k4 * 4 + 3] = xv.w;
        }
        __syncthreads();
        #pragma unroll
        for (int k = 0; k < 32; ++k) {
            float xv = xs[tid][k];
            #pragma unroll
            for (int c = 0; c < 32; ++c) acc[c] += xv * ws[k * 32 + c];
        }
    }
    if (node < n) {
        float dv = dis[node];
        float4* out4 = (float4*)(g + (size_t)node * 32);
        #pragma unroll
        for (int c4 = 0; c4 < 8; ++c4)
            out4[c4] = make_float4(acc[c4 * 4] * dv, acc[c4 * 4 + 1] * dv,
                                   acc[c4 * 4 + 2] * dv, acc[c4 * 4 + 3] * dv);
    }
}

// 32 -> 16
__global__ __launch_bounds__(128) void gemm2(const float* __restrict__ xin, const float* __restrict__ W,
                                             const float* __restrict__ dis, float* __restrict__ g, int n) {
    __shared__ float ws[32 * 16];
    __shared__ float xs[128][33];
    int tid = threadIdx.x;
    int node0 = blockIdx.x * 128;
    int node = node0 + tid;
    {
        int k = tid >> 2, c4 = tid & 3;  // 128 float4 = 512 floats
        float4 wv = *(const float4*)(W + (size_t)k * 16 + c4 * 4);
        *((float4*)(ws + k * 16 + c4 * 4)) = wv;
    }
    #pragma unroll
    for (int r = 0; r < 8; ++r) {
        int fi = tid + r * 128;
        int nd = fi >> 3, k4 = fi & 7;
        int gn = min(node0 + nd, n - 1);
        float4 xv = *(const float4*)(xin + (size_t)gn * 32 + k4 * 4);
        xs[nd][k4 * 4 + 0] = xv.x;
        xs[nd][k4 * 4 + 1] = xv.y;
        xs[nd][k4 * 4 + 2] = xv.z;
        xs[nd][k4 * 4 + 3] = xv.w;
    }
    __syncthreads();
    float acc[16];
    #pragma unroll
    for (int c = 0; c < 16; ++c) acc[c] = 0.f;
    #pragma unroll
    for (int k = 0; k < 32; ++k) {
        float xv = xs[tid][k];
        #pragma unroll
        for (int c = 0; c < 16; ++c) acc[c] += xv * ws[k * 16 + c];
    }
    if (node < n) {
        float dv = dis[node];
        float4* out4 = (float4*)(g + (size_t)node * 16);
        #pragma unroll
        for (int c4 = 0; c4 < 4; ++c4)
            out4[c4] = make_float4(acc[c4 * 4] * dv, acc[c4 * 4 + 1] * dv,
                                   acc[c4 * 4 + 2] * dv, acc[c4 * 4 + 3] * dv);
    }
}

// 16 -> 11, padded to stride 16 (cols 11..15 = 0)
__global__ __launch_bounds__(128) void gemm3(const float* __restrict__ xin, const float* __restrict__ W,
                                             const float* __restrict__ dis, float* __restrict__ g, int n) {
    __shared__ float ws[16 * 16];
    __shared__ float xs[128][17];
    int tid = threadIdx.x;
    int node0 = blockIdx.x * 128;
    int node = node0 + tid;
    #pragma unroll
    for (int fi = 0; fi < 2; ++fi) {
        int i = tid + fi * 128;  // 0..255
        int k = i >> 4, c = i & 15;
        ws[i] = (c < 11) ? W[(size_t)k * 11 + c] : 0.f;
    }
    #pragma unroll
    for (int r = 0; r < 4; ++r) {
        int fi = tid + r * 128;  // 0..511 float4
        int nd = fi >> 2, k4 = fi & 3;
        int gn = min(node0 + nd, n - 1);
        float4 xv = *(const float4*)(xin + (size_t)gn * 16 + k4 * 4);
        xs[nd][k4 * 4 + 0] = xv.x;
        xs[nd][k4 * 4 + 1] = xv.y;
        xs[nd][k4 * 4 + 2] = xv.z;
        xs[nd][k4 * 4 + 3] = xv.w;
    }
    __syncthreads();
    float acc[16];
    #pragma unroll
    for (int c = 0; c < 16; ++c) acc[c] = 0.f;
    #pragma unroll
    for (int k = 0; k < 16; ++k) {
        float xv = xs[tid][k];
        #pragma unroll
        for (int c = 0; c < 16; ++c) acc[c] += xv * ws[k * 16 + c];
    }
    if (node < n) {
        float dv = dis[node];
        float4* out4 = (float4*)(g + (size_t)node * 16);
        #pragma unroll
        for (int c4 = 0; c4 < 4; ++c4)
            out4[c4] = make_float4(acc[c4 * 4] * dv, acc[c4 * 4 + 1] * dv,
                                   acc[c4 * 4 + 2] * dv, acc[c4 * 4 + 3] * dv);
    }
}

// ==================== CSR gather: out[v] = (sum_edges g[s] + g[v]) * dis[v] + b ====================

template<int F, int LOGF, bool RELU>
__global__ __launch_bounds__(256) void gather(const int* __restrict__ csr_src,
        const int* __restrict__ start, const int* __restrict__ cnt,
        const float* __restrict__ g, const float* __restrict__ dis,
        const float* __restrict__ bias, float* __restrict__ out, int n) {
    int node = blockIdx.x * 4 + (threadIdx.x >> 6);
    if (node >= n) return;
    int lane = threadIdx.x & 63;
    int f = lane & (F - 1);
    int j = lane >> LOGF;
    const int EPI = 64 / F;
    int i0 = start[node], i1 = i0 + cnt[node];
    float acc = 0.f;
    for (int i = i0 + j; i < i1; i += EPI) {
        int s = csr_src[i];
        acc += g[(size_t)s * F + f];
    }
    #pragma unroll
    for (int m = F; m < 64; m <<= 1) acc += __shfl_xor(acc, m);
    float val = (acc + g[(size_t)node * F + f]) * dis[node] + bias[f];
    if (RELU) val = fmaxf(val, 0.f);
    if (lane < F) out[(size_t)node * F + f] = val;
}

// layer 3 gather + fused log_softmax (stride 16 in, 11 classes out)
__global__ __launch_bounds__(256) void gather3(const int* __restrict__ csr_src,
        const int* __restrict__ start, const int* __restrict__ cnt,
        const float* __restrict__ g, const float* __restrict__ dis,
        const float* __restrict__ bias, float* __restrict__ out, int n) {
    int node = blockIdx.x * 4 + (threadIdx.x >> 6);
    if (node >= n) return;
    int lane = threadIdx.x & 63;
    int f = lane & 15;
    int j = lane >> 4;
    int i0 = start[node], i1 = i0 + cnt[node];
    float acc = 0.f;
    for (int i = i0 + j; i < i1; i += 4) acc += g[(size_t)csr_src[i] * 16 + f];
    acc += __shfl_xor(acc, 16);
    acc += __shfl_xor(acc, 32);
    float val = (acc + g[(size_t)node * 16 + f]) * dis[node] + ((f < 11) ? bias[f] : 0.f);
    float vm = (f < 11) ? val : -3.0e38f;
    #pragma unroll
    for (int m = 1; m < 16; m <<= 1) vm = fmaxf(vm, __shfl_xor(vm, m));
    float ex = (f < 11) ? __expf(val - vm) : 0.f;
    float sum = ex;
    #pragma unroll
    for (int m = 1; m < 16; m <<= 1) sum += __shfl_xor(sum, m);
    if (lane < 11) out[(size_t)node * 11 + f] = val - (__logf(sum) + vm);
}

// ==================== launch ====================

extern "C" void kernel_launch(void* const* d_in, const int* in_sizes, int n_in,
                              void* d_out, int out_size, void* d_ws, size_t ws_size,
                              hipStream_t stream) {
    const float* x  = (const float*)d_in[0];
    const int*   ei = (const int*)d_in[1];
    const float* W1 = (const float*)d_in[2];
    const float* b1 = (const float*)d_in[3];
    const float* W2 = (const float*)d_in[4];
    const float* b2 = (const float*)d_in[5];
    const float* W3 = (const float*)d_in[6];
    const float* b3 = (const float*)d_in[7];
    float* out = (float*)d_out;

    const int n = in_sizes[0] / 512;
    const int E = in_sizes[1] / 2;
    const int* src = ei;
    const int* dst = ei + E;

    // workspace layout (elements of 4B)
    int* ws0 = (int*)d_ws;
    int*   cnt     = ws0;                       // N
    int*   start   = ws0 + (size_t)n;           // N
    int*   fill    = ws0 + (size_t)2 * n;       // N
    float* dis     = (float*)(ws0 + (size_t)3 * n);  // N
    int*   csr_src = ws0 + (size_t)4 * n;       // E
    float* bufA    = (float*)(ws0 + (size_t)4 * n + E);  // N*32
    float* bufB    = bufA + (size_t)n * 32;              // N*32
    int*   blksum  = (int*)(bufB + (size_t)n * 32);      // nb ints

    const int nb = (n + SCAN_ELEMS - 1) / SCAN_ELEMS;  // 98 <= 256

    hipMemsetAsync(cnt, 0, (size_t)n * 4, stream);
    hipMemsetAsync(fill, 0, (size_t)n * 4, stream);
    count_deg<<<(E + 255) / 256, 256, 0, stream>>>(dst, cnt, E);
    deg_to_dis<<<(n + 255) / 256, 256, 0, stream>>>(cnt, dis, n);

    // exclusive scan of cnt -> start
    scan1<<<nb, 256, 0, stream>>>(cnt, start, blksum, n);
    scan2<<<1, 256, 0, stream>>>(blksum, nb);
    scan3<<<(n + 255) / 256, 256, 0, stream>>>(start, blksum, n);

    fill_csr<<<(E + 255) / 256, 256, 0, stream>>>(src, dst, start, fill, csr_src, E);

    // layer 1: g1 = (x@W1)*dis -> bufA ; out1 = relu(gather) -> bufB
    gemm1<<<(n + 127) / 128, 128, 0, stream>>>(x, W1, dis, bufA, n);
    gather<32, 5, true><<<(n + 3) / 4, 256, 0, stream>>>(csr_src, start, cnt, bufA, dis, b1, bufB, n);

    // layer 2: g2 = (out1@W2)*dis -> bufA ; out2 = relu(gather) -> bufB
    gemm2<<<(n + 127) / 128, 128, 0, stream>>>(bufB, W2, dis, bufA, n);
    gather<16, 4, true><<<(n + 3) / 4, 256, 0, stream>>>(csr_src, start, cnt, bufA, dis, b2, bufB, n);

    // layer 3: g3 = (out2@W3)*dis (stride 16, padded) -> bufA ; gather+log_softmax -> out
    gemm3<<<(n + 127) / 128, 128, 0, stream>>>(bufB, W3, dis, bufA, n);
    gather3<<<(n + 3) / 4, 256, 0, stream>>>(csr_src, start, cnt, bufA, dis, b3, out, n);
}